// Round 20
// baseline (371.225 us; speedup 1.0000x reference)
//
#include <hip/hip_runtime.h>
#include <hip/hip_bf16.h>

// Problem constants
#define TT   256
#define BB   1024
#define OBS  64
#define HH   128
#define AA   32
#define NN   (TT*BB)          // 262144

typedef __bf16 bf16x8 __attribute__((ext_vector_type(8)));
typedef __bf16 bf16x4 __attribute__((ext_vector_type(4)));
typedef float  f32x4  __attribute__((ext_vector_type(4)));

__device__ __forceinline__ float sigmoidf_(float x) {
    return 1.0f / (1.0f + __expf(-x));
}
__device__ __forceinline__ float tanhf_(float x) {
    float ax = fabsf(x);
    float e  = __expf(-2.0f * ax);
    float t  = (1.0f - e) / (1.0f + e);
    return copysignf(t, x);
}
__device__ __forceinline__ __hip_bfloat16 f2b(float v) { return __float2bfloat16(v); }
__device__ __forceinline__ bf16x8 ldb(const __hip_bfloat16* p) {
    return *reinterpret_cast<const bf16x8*>(p);
}
__device__ __forceinline__ f32x4 mm16(bf16x8 a, bf16x8 b, f32x4 c) {
    return __builtin_amdgcn_mfma_f32_16x16x32_bf16(a, b, c, 0, 0, 0);
}
__device__ __forceinline__ bf16x8 cvtrow8(const float* p) {
    float4 a = *(const float4*)p, b = *(const float4*)(p + 4);
    union { bf16x8 v; __hip_bfloat16 h[8]; } u;
    u.h[0]=f2b(a.x); u.h[1]=f2b(a.y); u.h[2]=f2b(a.z); u.h[3]=f2b(a.w);
    u.h[4]=f2b(b.x); u.h[5]=f2b(b.y); u.h[6]=f2b(b.z); u.h[7]=f2b(b.w);
    return u.v;
}

// Weight scratch layout (in d_out, bytes; overwritten later by heads' lp region):
//   [0,      131072)  wih16  [512][128] bf16  (w_ih, no transpose needed)
//   [131072, 147456)  w1t16  [128][64]  bf16  (W1 transposed)
//   [147456, 180224)  w2t16  [128][128] bf16  (W2 transposed)
//   [180224, 182272)  sbihq  [512]      f32   (b_ih+b_hh, gate-interleaved)

// ---------------------------------------------------------------------------
// Kernel 0: prep — bf16 weight conversion/transpose + interleaved bias.
// ---------------------------------------------------------------------------
__global__ __launch_bounds__(512) void prep_kernel(
    const float* __restrict__ w_ih, const float* __restrict__ W1,
    const float* __restrict__ W2,
    const float* __restrict__ b_ih, const float* __restrict__ b_hh,
    __hip_bfloat16* __restrict__ wih16, __hip_bfloat16* __restrict__ w1t16,
    __hip_bfloat16* __restrict__ w2t16, float* __restrict__ sbihq)
{
    const int idx0 = blockIdx.x * 512 + threadIdx.x;
    const int stride = gridDim.x * 512;
    for (int i = idx0; i < 512*128; i += stride) wih16[i] = f2b(w_ih[i]);
    for (int i = idx0; i < 128*64;  i += stride) {
        int n = i >> 6, k = i & 63;
        w1t16[i] = f2b(W1[k*128 + n]);
    }
    for (int i = idx0; i < 128*128; i += stride) {
        int n = i >> 7, k = i & 127;
        w2t16[i] = f2b(W2[k*128 + n]);
    }
    for (int i = idx0; i < 512; i += stride) {
        int un = i >> 2, gt = i & 3;
        sbihq[i] = b_ih[gt*128 + un] + b_hh[gt*128 + un];
    }
}

// ---------------------------------------------------------------------------
// Kernel 1: trunk — r18 structure (unit-split L3); r19/r20: xg stores are
// NON-TEMPORAL (write-once stream, consumed by lstm much later — avoids L2
// write-allocate pollution against the weight reads).
// ---------------------------------------------------------------------------
__global__ __launch_bounds__(512, 4) void trunk_kernel(
    const float* __restrict__ x,
    const float* __restrict__ b1, const float* __restrict__ b2,
    const __hip_bfloat16* __restrict__ wih16,
    const __hip_bfloat16* __restrict__ w1t16,
    const __hip_bfloat16* __restrict__ w2t16,
    const float* __restrict__ sbihq,
    __hip_bfloat16* __restrict__ xg)
{
    __shared__ __align__(16) __hip_bfloat16 hwb[16][16][136]; // 69632 B

    const int tid  = threadIdx.x;
    const int lane = tid & 63;
    const int w    = tid >> 6;
    const int lm   = lane & 15;
    const int lko  = lane >> 4;
    const size_t r0 = (size_t)blockIdx.x * 256;

    // ---- L1: h1 = relu(x @ W1 + b1), K=64; wave-private tiles 2w, 2w+1 ----
    {
        bf16x8 a0[2], a1[2];
        #pragma unroll
        for (int t = 0; t < 2; ++t) {
            const float* xr = x + (r0 + (w*2 + t)*16 + lm) * OBS;
            a0[t] = cvtrow8(xr + lko*8);
            a1[t] = cvtrow8(xr + 32 + lko*8);
        }
        #pragma unroll
        for (int ct = 0; ct < 8; ++ct) {
            bf16x8 bv0 = ldb(w1t16 + (ct*16 + lm)*64 + lko*8);
            bf16x8 bv1 = ldb(w1t16 + (ct*16 + lm)*64 + 32 + lko*8);
            float bias = b1[ct*16 + lm];
            #pragma unroll
            for (int t = 0; t < 2; ++t) {
                f32x4 acc = {0.f, 0.f, 0.f, 0.f};
                acc = mm16(a0[t], bv0, acc);
                acc = mm16(a1[t], bv1, acc);
                #pragma unroll
                for (int rr = 0; rr < 4; ++rr)
                    hwb[w*2 + t][lko*4 + rr][ct*16 + lm] =
                        f2b(fmaxf(acc[rr] + bias, 0.f));
            }
        }
    }

    // ---- L2: h2 = relu(h1 @ W2 + b2), K=128; in-place, wave-private ----
    {
        bf16x8 a[2][4];
        #pragma unroll
        for (int t = 0; t < 2; ++t)
            #pragma unroll
            for (int kt = 0; kt < 4; ++kt)
                a[t][kt] = ldb(&hwb[w*2 + t][lm][kt*32 + lko*8]);
        #pragma unroll
        for (int ct = 0; ct < 8; ++ct) {
            bf16x8 bw[4];
            #pragma unroll
            for (int kt = 0; kt < 4; ++kt)
                bw[kt] = ldb(w2t16 + (ct*16 + lm)*128 + kt*32 + lko*8);
            float bias = b2[ct*16 + lm];
            #pragma unroll
            for (int t = 0; t < 2; ++t) {
                f32x4 acc = {0.f, 0.f, 0.f, 0.f};
                #pragma unroll
                for (int kt = 0; kt < 4; ++kt)
                    acc = mm16(a[t][kt], bw[kt], acc);
                #pragma unroll
                for (int rr = 0; rr < 4; ++rr)
                    hwb[w*2 + t][lko*4 + rr][ct*16 + lm] =
                        f2b(fmaxf(acc[rr] + bias, 0.f));
            }
        }
    }

    __syncthreads();   // L3 reads other waves' h2 tiles

    // ---- L3 (unit-split): wave w -> unit cols u = w*16+lm, all 16 tiles ----
    {
        const int u = w*16 + lm;
        bf16x8 wih[4][4];
        #pragma unroll
        for (int gt = 0; gt < 4; ++gt)
            #pragma unroll
            for (int kt = 0; kt < 4; ++kt)
                wih[gt][kt] =
                    ldb(wih16 + (size_t)(gt*128 + u)*128 + kt*32 + lko*8);
        const f32x4 bq = *(const f32x4*)&sbihq[u*4];

        #pragma unroll 1
        for (int rt = 0; rt < 16; ++rt) {
            f32x4 acc[4];
            #pragma unroll
            for (int gt = 0; gt < 4; ++gt) acc[gt] = (f32x4){0.f, 0.f, 0.f, 0.f};
            #pragma unroll
            for (int kt = 0; kt < 4; ++kt) {
                bf16x8 a = ldb(&hwb[rt][lm][kt*32 + lko*8]);
                #pragma unroll
                for (int gt = 0; gt < 4; ++gt)
                    acc[gt] = mm16(a, wih[gt][kt], acc[gt]);
            }
            #pragma unroll
            for (int rr = 0; rr < 4; ++rr) {
                union { bf16x4 v; __hip_bfloat16 h[4]; } hp;
                hp.h[0] = f2b(acc[0][rr] + bq[0]);
                hp.h[1] = f2b(acc[1][rr] + bq[1]);
                hp.h[2] = f2b(acc[2][rr] + bq[2]);
                hp.h[3] = f2b(acc[3][rr] + bq[3]);
                __builtin_nontemporal_store(hp.v,
                    (bf16x4*)(xg + (r0 + rt*16 + lko*4 + rr)*512 + u*4));
            }
        }
    }
}

// ---------------------------------------------------------------------------
// Kernel 2: LSTM scan — r17 structure (zero-shuffle gate delivery). r20:
// per-step 64-bit address arithmetic strength-reduced to pointer increments;
// hst store non-temporal via unsigned short (builtin rejects __hip_bfloat16*).
// ---------------------------------------------------------------------------
__global__ __launch_bounds__(512) void lstm_kernel(
    const __hip_bfloat16* __restrict__ xg,  // [N][128][4] bf16 (bias included)
    __hip_bfloat16* __restrict__ hst,       // alias of xg: h_t -> row n slots 0..127
    const float* __restrict__ w_hh,         // [512,128]
    const int* __restrict__ done,           // [N]
    const float* __restrict__ h0,
    const float* __restrict__ c0,
    float* __restrict__ out)                // lp N | ent N | val N | hN B*H | cN B*H
{
    __shared__ __align__(16) __hip_bfloat16 htile[2][16][136]; // raw h (bf16)

    const int tid  = threadIdx.x;
    const int lane = tid & 63;
    const int w    = tid >> 6;       // wave 0..7
    const int lm   = lane & 15;      // MFMA D-col id
    const int lko  = lane >> 4;      // k-octet / unit-quad id
    const int b0   = blockIdx.x * 4;
    const int b    = lm >> 2;        // this lane's batch (0..3)
    const int s    = lm & 3;         // acc register select
    const int un   = w * 16 + lko * 4 + s;   // this lane's unit (0..127)

    // ---- A-frags: w_hh rows gt*128 + w*16 + lm ----
    bf16x8 wf[4][4];
    #pragma unroll
    for (int gt = 0; gt < 4; ++gt) {
        #pragma unroll
        for (int kt = 0; kt < 4; ++kt) {
            const float* p = w_hh + (size_t)(gt*128 + w*16 + lm)*HH + kt*32 + lko*8;
            wf[gt][kt] = cvtrow8(p);
        }
    }

    // ---- init htile[0] rows 0..3 from h0; rows 4..15 of both buffers = 0 ----
    {
        int r = tid >> 7, uu2 = tid & 127;
        htile[0][r][uu2] = f2b(h0[(size_t)(b0 + r)*HH + uu2]);
        for (int idx = tid; idx < 12*136; idx += 512) {
            (&htile[0][4][0])[idx] = f2b(0.0f);
            (&htile[1][4][0])[idx] = f2b(0.0f);
        }
    }
    // ---- per-lane state: c,h for (batch b, unit un) ----
    float c_reg = c0[(size_t)(b0 + b)*HH + un];
    float h_reg = h0[(size_t)(b0 + b)*HH + un];

    // ---- walking pointers (strength-reduced addressing) ----
    const __hip_bfloat16* xq_p = xg + (size_t)(b0 + b)*512 + un*4;  // step 0
    unsigned short* hs_p =
        (unsigned short*)hst + (size_t)(b0 + b)*512 + un;           // step 0
    const int* dn_p = done + b0 + b;                                // step 0
    const size_t XSTRIDE = (size_t)BB * 512;                        // per step

    // ---- prefetch operands for it=0 ----
    int dn_c = dn_p[0];
    bf16x4 xq_c = *(const bf16x4*)xq_p;

    __syncthreads();

    for (int it = 0; it < TT; ++it) {
        // prefetch operands for it+1 (hidden under the MFMA + gate work)
        int dn_n = 0;
        bf16x4 xq_n = {};
        if (it < TT - 1) {
            dn_n = dn_p[BB];
            xq_n = *(const bf16x4*)(xq_p + XSTRIDE);
        }

        const int cur = it & 1, nxt = cur ^ 1;

        // B-frags: batch-replicated — col lm sources batch lm>>2's h row.
        bf16x8 hb[4];
        #pragma unroll
        for (int kt = 0; kt < 4; ++kt)
            hb[kt] = ldb(&htile[cur][b][kt*32 + lko*8]);

        // 16 MFMA: acc[gt][r] = gate gt of unit w*16+lko*4+r, batch b
        f32x4 acc[4];
        #pragma unroll
        for (int gt = 0; gt < 4; ++gt) acc[gt] = (f32x4){0.f, 0.f, 0.f, 0.f};
        #pragma unroll
        for (int kt = 0; kt < 4; ++kt)
            #pragma unroll
            for (int gt = 0; gt < 4; ++gt)
                acc[gt] = mm16(wf[gt][kt], hb[kt], acc[gt]);

        // in-register select of this lane's 4 gates (reg s of each acc[gt])
        float g4[4];
        #pragma unroll
        for (int gt = 0; gt < 4; ++gt) {
            float a01 = (s & 1) ? acc[gt][1] : acc[gt][0];
            float a23 = (s & 1) ? acc[gt][3] : acc[gt][2];
            g4[gt]    = (s & 2) ? a23 : a01;
        }

        const float keep = dn_c ? 0.0f : 1.0f;
        float gi = fmaf(g4[0], keep, (float)xq_c[0]);
        float gf = fmaf(g4[1], keep, (float)xq_c[1]);
        float gg = fmaf(g4[2], keep, (float)xq_c[2]);
        float go = fmaf(g4[3], keep, (float)xq_c[3]);
        float cp = c_reg * keep;
        float cn = sigmoidf_(gf) * cp + sigmoidf_(gi) * tanhf_(gg);
        float hn = sigmoidf_(go) * tanhf_(cn);
        c_reg = cn;
        h_reg = hn;
        __hip_bfloat16 hnb = f2b(hn);
        htile[nxt][b][un] = hnb;
        // store h_t (bf16 bits as u16) into the consumed xg row — NT stream
        __builtin_nontemporal_store(*(unsigned short*)&hnb, hs_p);

        __syncthreads();

        dn_c = dn_n;
        xq_c = xq_n;
        xq_p += XSTRIDE;
        hs_p += XSTRIDE;
        dn_p += BB;
    }

    // ---- final states (each lane owns one (b,un) pair) ----
    out[3*(size_t)NN + (size_t)(b0 + b)*HH + un] = h_reg;
    out[3*(size_t)NN + (size_t)BB*HH + (size_t)(b0 + b)*HH + un] = c_reg;
}

// ---------------------------------------------------------------------------
// Kernel 3: fused heads — r20: 8 row-tiles per block (grid 256) to amortize
// WaT/WcB staging and launch tail; otherwise unchanged.
// ---------------------------------------------------------------------------
__global__ __launch_bounds__(512) void heads_kernel(
    const __hip_bfloat16* __restrict__ hbuf, // xg base; row n -> hbuf+n*512, 128 bf16
    const int* __restrict__ mask,            // [N,32] bool as int32
    const int* __restrict__ action,          // [N]
    const float* __restrict__ Wa,            // [128,32]
    const float* __restrict__ ba,
    const float* __restrict__ Wc,            // [128]
    const float* __restrict__ bc,
    float* __restrict__ out)
{
    __shared__ __align__(16) __hip_bfloat16 WaT[32][136]; // transposed Wa
    __shared__ __align__(16) __hip_bfloat16 WcB[128];

    const int tid  = threadIdx.x;
    const int lane = tid & 63;
    const int w    = tid >> 6;
    const int lm   = lane & 15;
    const int lko  = lane >> 4;

    // stage WaT[j][k] = Wa[k][j], WcB (once per block)
    for (int idx = tid; idx < 128*32; idx += 512) {
        int k = idx >> 5, j = idx & 31;
        WaT[j][k] = f2b(Wa[idx]);
    }
    if (tid < 128) WcB[tid] = f2b(Wc[tid]);
    __syncthreads();

    // B-frags from LDS: Wa cols lm and 16+lm; Wc in col 0
    bf16x8 wa0[4], wa1[4], wcf[4];
    #pragma unroll
    for (int kt = 0; kt < 4; ++kt) {
        wa0[kt] = ldb(&WaT[lm][kt*32 + lko*8]);
        wa1[kt] = ldb(&WaT[16 + lm][kt*32 + lko*8]);
        bf16x8 z = {};
        wcf[kt] = (lm == 0) ? ldb(&WcB[kt*32 + lko*8]) : z;
    }
    const float ba0 = ba[lm], ba1 = ba[16 + lm], bcv = bc[0];

    #pragma unroll 1
    for (int rt = 0; rt < 8; ++rt) {
        const size_t nbase = (size_t)blockIdx.x * 1024 + rt * 128 + w * 16;

        // A-frags: 16 h-rows
        bf16x8 a[4];
        #pragma unroll
        for (int kt = 0; kt < 4; ++kt)
            a[kt] = ldb(hbuf + (nbase + lm)*512 + kt*32 + lko*8);

        f32x4 t0 = {0.f,0.f,0.f,0.f}, t1 = {0.f,0.f,0.f,0.f}, tv = {0.f,0.f,0.f,0.f};
        #pragma unroll
        for (int kt = 0; kt < 4; ++kt) {
            t0 = mm16(a[kt], wa0[kt], t0);
            t1 = mm16(a[kt], wa1[kt], t1);
            tv = mm16(a[kt], wcf[kt], tv);
        }

        #pragma unroll
        for (int r = 0; r < 4; ++r) {
            const size_t n = nbase + lko*4 + r;
            float lg0 = t0[r] + ba0;
            float lg1 = t1[r] + ba1;
            if (mask[n*32 + lm] == 0)      lg0 = -1e8f;
            if (mask[n*32 + 16 + lm] == 0) lg1 = -1e8f;

            float mx = fmaxf(lg0, lg1);
            #pragma unroll
            for (int off = 8; off > 0; off >>= 1)
                mx = fmaxf(mx, __shfl_xor(mx, off, 16));
            float e0 = __expf(lg0 - mx), e1 = __expf(lg1 - mx);
            float s = e0 + e1;
            #pragma unroll
            for (int off = 8; off > 0; off >>= 1)
                s += __shfl_xor(s, off, 16);
            float lse = __logf(s);
            float lp0 = lg0 - mx - lse;
            float lp1 = lg1 - mx - lse;
            float entl = -(e0 * lp0 + e1 * lp1) / s;
            #pragma unroll
            for (int off = 8; off > 0; off >>= 1)
                entl += __shfl_xor(entl, off, 16);

            int act = action[n];
            if (lm == act)      out[n] = lp0;
            if (16 + lm == act) out[n] = lp1;
            if (lm == 0) {
                out[(size_t)NN + n] = entl;
                out[2*(size_t)NN + n] = tv[r] + bcv;
            }
        }
    }
}

extern "C" void kernel_launch(void* const* d_in, const int* in_sizes, int n_in,
                              void* d_out, int out_size, void* d_ws, size_t ws_size,
                              hipStream_t stream) {
    const float* x      = (const float*)d_in[0];
    const int*   done   = (const int*)d_in[1];
    const int*   action = (const int*)d_in[2];
    const int*   mask   = (const int*)d_in[3];
    const float* h0     = (const float*)d_in[4];
    const float* c0     = (const float*)d_in[5];
    const float* W1     = (const float*)d_in[6];
    const float* b1     = (const float*)d_in[7];
    const float* W2     = (const float*)d_in[8];
    const float* b2     = (const float*)d_in[9];
    const float* w_ih   = (const float*)d_in[10];
    const float* w_hh   = (const float*)d_in[11];
    const float* b_ih   = (const float*)d_in[12];
    const float* b_hh   = (const float*)d_in[13];
    const float* Wa     = (const float*)d_in[14];
    const float* ba     = (const float*)d_in[15];
    const float* Wc     = (const float*)d_in[16];
    const float* bc     = (const float*)d_in[17];

    __hip_bfloat16* xg = (__hip_bfloat16*)d_ws;  // [N,512] bf16 = 256 MiB

    // weight scratch in d_out (first 182KB; later overwritten by heads' lp)
    char* wb = (char*)d_out;
    __hip_bfloat16* wih16 = (__hip_bfloat16*)(wb);
    __hip_bfloat16* w1t16 = (__hip_bfloat16*)(wb + 131072);
    __hip_bfloat16* w2t16 = (__hip_bfloat16*)(wb + 147456);
    float*          sbihq = (float*)(wb + 180224);

    prep_kernel<<<32, 512, 0, stream>>>(w_ih, W1, W2, b_ih, b_hh,
                                        wih16, w1t16, w2t16, sbihq);
    trunk_kernel<<<NN/256, 512, 0, stream>>>(x, b1, b2, wih16, w1t16, w2t16,
                                             sbihq, xg);
    lstm_kernel<<<BB/4, 512, 0, stream>>>(xg, xg, w_hh, done, h0, c0, (float*)d_out);
    heads_kernel<<<NN/1024, 512, 0, stream>>>(xg, mask, action, Wa, ba, Wc, bc,
                                              (float*)d_out);
}

// Round 21
// 352.115 us; speedup vs baseline: 1.0543x; 1.0543x over previous
//
#include <hip/hip_runtime.h>
#include <hip/hip_bf16.h>

// Problem constants
#define TT   256
#define BB   1024
#define OBS  64
#define HH   128
#define AA   32
#define NN   (TT*BB)          // 262144

typedef __bf16 bf16x8 __attribute__((ext_vector_type(8)));
typedef __bf16 bf16x4 __attribute__((ext_vector_type(4)));
typedef float  f32x4  __attribute__((ext_vector_type(4)));

__device__ __forceinline__ float sigmoidf_(float x) {
    return 1.0f / (1.0f + __expf(-x));
}
__device__ __forceinline__ float tanhf_(float x) {
    float ax = fabsf(x);
    float e  = __expf(-2.0f * ax);
    float t  = (1.0f - e) / (1.0f + e);
    return copysignf(t, x);
}
__device__ __forceinline__ __hip_bfloat16 f2b(float v) { return __float2bfloat16(v); }
__device__ __forceinline__ bf16x8 ldb(const __hip_bfloat16* p) {
    return *reinterpret_cast<const bf16x8*>(p);
}
__device__ __forceinline__ f32x4 mm16(bf16x8 a, bf16x8 b, f32x4 c) {
    return __builtin_amdgcn_mfma_f32_16x16x32_bf16(a, b, c, 0, 0, 0);
}
__device__ __forceinline__ bf16x8 cvtrow8(const float* p) {
    float4 a = *(const float4*)p, b = *(const float4*)(p + 4);
    union { bf16x8 v; __hip_bfloat16 h[8]; } u;
    u.h[0]=f2b(a.x); u.h[1]=f2b(a.y); u.h[2]=f2b(a.z); u.h[3]=f2b(a.w);
    u.h[4]=f2b(b.x); u.h[5]=f2b(b.y); u.h[6]=f2b(b.z); u.h[7]=f2b(b.w);
    return u.v;
}

// Weight scratch layout (in d_out, bytes; overwritten later by heads' lp region):
//   [0,      131072)  wih16  [512][128] bf16  (w_ih, no transpose needed)
//   [131072, 147456)  w1t16  [128][64]  bf16  (W1 transposed)
//   [147456, 180224)  w2t16  [128][128] bf16  (W2 transposed)
//   [180224, 182272)  sbihq  [512]      f32   (b_ih+b_hh, gate-interleaved)

// ---------------------------------------------------------------------------
// Kernel 0: prep — bf16 weight conversion/transpose + interleaved bias.
// ---------------------------------------------------------------------------
__global__ __launch_bounds__(512) void prep_kernel(
    const float* __restrict__ w_ih, const float* __restrict__ W1,
    const float* __restrict__ W2,
    const float* __restrict__ b_ih, const float* __restrict__ b_hh,
    __hip_bfloat16* __restrict__ wih16, __hip_bfloat16* __restrict__ w1t16,
    __hip_bfloat16* __restrict__ w2t16, float* __restrict__ sbihq)
{
    const int idx0 = blockIdx.x * 512 + threadIdx.x;
    const int stride = gridDim.x * 512;
    for (int i = idx0; i < 512*128; i += stride) wih16[i] = f2b(w_ih[i]);
    for (int i = idx0; i < 128*64;  i += stride) {
        int n = i >> 6, k = i & 63;
        w1t16[i] = f2b(W1[k*128 + n]);
    }
    for (int i = idx0; i < 128*128; i += stride) {
        int n = i >> 7, k = i & 127;
        w2t16[i] = f2b(W2[k*128 + n]);
    }
    for (int i = idx0; i < 512; i += stride) {
        int un = i >> 2, gt = i & 3;
        sbihq[i] = b_ih[gt*128 + un] + b_hh[gt*128 + un];
    }
}

// ---------------------------------------------------------------------------
// Kernel 1: trunk — r18 form exactly (unit-split L3, PLAIN xg stores; the
// r20 non-temporal store experiment regressed ~10-15us and is reverted).
// ---------------------------------------------------------------------------
__global__ __launch_bounds__(512, 4) void trunk_kernel(
    const float* __restrict__ x,
    const float* __restrict__ b1, const float* __restrict__ b2,
    const __hip_bfloat16* __restrict__ wih16,
    const __hip_bfloat16* __restrict__ w1t16,
    const __hip_bfloat16* __restrict__ w2t16,
    const float* __restrict__ sbihq,
    __hip_bfloat16* __restrict__ xg)
{
    __shared__ __align__(16) __hip_bfloat16 hwb[16][16][136]; // 69632 B

    const int tid  = threadIdx.x;
    const int lane = tid & 63;
    const int w    = tid >> 6;
    const int lm   = lane & 15;
    const int lko  = lane >> 4;
    const size_t r0 = (size_t)blockIdx.x * 256;

    // ---- L1: h1 = relu(x @ W1 + b1), K=64; wave-private tiles 2w, 2w+1 ----
    {
        bf16x8 a0[2], a1[2];
        #pragma unroll
        for (int t = 0; t < 2; ++t) {
            const float* xr = x + (r0 + (w*2 + t)*16 + lm) * OBS;
            a0[t] = cvtrow8(xr + lko*8);
            a1[t] = cvtrow8(xr + 32 + lko*8);
        }
        #pragma unroll
        for (int ct = 0; ct < 8; ++ct) {
            bf16x8 bv0 = ldb(w1t16 + (ct*16 + lm)*64 + lko*8);
            bf16x8 bv1 = ldb(w1t16 + (ct*16 + lm)*64 + 32 + lko*8);
            float bias = b1[ct*16 + lm];
            #pragma unroll
            for (int t = 0; t < 2; ++t) {
                f32x4 acc = {0.f, 0.f, 0.f, 0.f};
                acc = mm16(a0[t], bv0, acc);
                acc = mm16(a1[t], bv1, acc);
                #pragma unroll
                for (int rr = 0; rr < 4; ++rr)
                    hwb[w*2 + t][lko*4 + rr][ct*16 + lm] =
                        f2b(fmaxf(acc[rr] + bias, 0.f));
            }
        }
    }

    // ---- L2: h2 = relu(h1 @ W2 + b2), K=128; in-place, wave-private ----
    {
        bf16x8 a[2][4];
        #pragma unroll
        for (int t = 0; t < 2; ++t)
            #pragma unroll
            for (int kt = 0; kt < 4; ++kt)
                a[t][kt] = ldb(&hwb[w*2 + t][lm][kt*32 + lko*8]);
        #pragma unroll
        for (int ct = 0; ct < 8; ++ct) {
            bf16x8 bw[4];
            #pragma unroll
            for (int kt = 0; kt < 4; ++kt)
                bw[kt] = ldb(w2t16 + (ct*16 + lm)*128 + kt*32 + lko*8);
            float bias = b2[ct*16 + lm];
            #pragma unroll
            for (int t = 0; t < 2; ++t) {
                f32x4 acc = {0.f, 0.f, 0.f, 0.f};
                #pragma unroll
                for (int kt = 0; kt < 4; ++kt)
                    acc = mm16(a[t][kt], bw[kt], acc);
                #pragma unroll
                for (int rr = 0; rr < 4; ++rr)
                    hwb[w*2 + t][lko*4 + rr][ct*16 + lm] =
                        f2b(fmaxf(acc[rr] + bias, 0.f));
            }
        }
    }

    __syncthreads();   // L3 reads other waves' h2 tiles

    // ---- L3 (unit-split): wave w -> unit cols u = w*16+lm, all 16 tiles ----
    {
        const int u = w*16 + lm;
        bf16x8 wih[4][4];
        #pragma unroll
        for (int gt = 0; gt < 4; ++gt)
            #pragma unroll
            for (int kt = 0; kt < 4; ++kt)
                wih[gt][kt] =
                    ldb(wih16 + (size_t)(gt*128 + u)*128 + kt*32 + lko*8);
        const f32x4 bq = *(const f32x4*)&sbihq[u*4];

        #pragma unroll 1
        for (int rt = 0; rt < 16; ++rt) {
            f32x4 acc[4];
            #pragma unroll
            for (int gt = 0; gt < 4; ++gt) acc[gt] = (f32x4){0.f, 0.f, 0.f, 0.f};
            #pragma unroll
            for (int kt = 0; kt < 4; ++kt) {
                bf16x8 a = ldb(&hwb[rt][lm][kt*32 + lko*8]);
                #pragma unroll
                for (int gt = 0; gt < 4; ++gt)
                    acc[gt] = mm16(a, wih[gt][kt], acc[gt]);
            }
            #pragma unroll
            for (int rr = 0; rr < 4; ++rr) {
                union { bf16x4 v; __hip_bfloat16 h[4]; } hp;
                hp.h[0] = f2b(acc[0][rr] + bq[0]);
                hp.h[1] = f2b(acc[1][rr] + bq[1]);
                hp.h[2] = f2b(acc[2][rr] + bq[2]);
                hp.h[3] = f2b(acc[3][rr] + bq[3]);
                *(bf16x4*)(xg + (r0 + rt*16 + lko*4 + rr)*512 + u*4) = hp.v;
            }
        }
    }
}

// ---------------------------------------------------------------------------
// Kernel 2: LSTM scan — unchanged from r20 (best: 220us). Zero-shuffle gate
// delivery; walking pointers; NT hst store via unsigned short.
// ---------------------------------------------------------------------------
__global__ __launch_bounds__(512) void lstm_kernel(
    const __hip_bfloat16* __restrict__ xg,  // [N][128][4] bf16 (bias included)
    __hip_bfloat16* __restrict__ hst,       // alias of xg: h_t -> row n slots 0..127
    const float* __restrict__ w_hh,         // [512,128]
    const int* __restrict__ done,           // [N]
    const float* __restrict__ h0,
    const float* __restrict__ c0,
    float* __restrict__ out)                // lp N | ent N | val N | hN B*H | cN B*H
{
    __shared__ __align__(16) __hip_bfloat16 htile[2][16][136]; // raw h (bf16)

    const int tid  = threadIdx.x;
    const int lane = tid & 63;
    const int w    = tid >> 6;       // wave 0..7
    const int lm   = lane & 15;      // MFMA D-col id
    const int lko  = lane >> 4;      // k-octet / unit-quad id
    const int b0   = blockIdx.x * 4;
    const int b    = lm >> 2;        // this lane's batch (0..3)
    const int s    = lm & 3;         // acc register select
    const int un   = w * 16 + lko * 4 + s;   // this lane's unit (0..127)

    // ---- A-frags: w_hh rows gt*128 + w*16 + lm ----
    bf16x8 wf[4][4];
    #pragma unroll
    for (int gt = 0; gt < 4; ++gt) {
        #pragma unroll
        for (int kt = 0; kt < 4; ++kt) {
            const float* p = w_hh + (size_t)(gt*128 + w*16 + lm)*HH + kt*32 + lko*8;
            wf[gt][kt] = cvtrow8(p);
        }
    }

    // ---- init htile[0] rows 0..3 from h0; rows 4..15 of both buffers = 0 ----
    {
        int r = tid >> 7, uu2 = tid & 127;
        htile[0][r][uu2] = f2b(h0[(size_t)(b0 + r)*HH + uu2]);
        for (int idx = tid; idx < 12*136; idx += 512) {
            (&htile[0][4][0])[idx] = f2b(0.0f);
            (&htile[1][4][0])[idx] = f2b(0.0f);
        }
    }
    // ---- per-lane state: c,h for (batch b, unit un) ----
    float c_reg = c0[(size_t)(b0 + b)*HH + un];
    float h_reg = h0[(size_t)(b0 + b)*HH + un];

    // ---- walking pointers (strength-reduced addressing) ----
    const __hip_bfloat16* xq_p = xg + (size_t)(b0 + b)*512 + un*4;  // step 0
    unsigned short* hs_p =
        (unsigned short*)hst + (size_t)(b0 + b)*512 + un;           // step 0
    const int* dn_p = done + b0 + b;                                // step 0
    const size_t XSTRIDE = (size_t)BB * 512;                        // per step

    // ---- prefetch operands for it=0 ----
    int dn_c = dn_p[0];
    bf16x4 xq_c = *(const bf16x4*)xq_p;

    __syncthreads();

    for (int it = 0; it < TT; ++it) {
        // prefetch operands for it+1 (hidden under the MFMA + gate work)
        int dn_n = 0;
        bf16x4 xq_n = {};
        if (it < TT - 1) {
            dn_n = dn_p[BB];
            xq_n = *(const bf16x4*)(xq_p + XSTRIDE);
        }

        const int cur = it & 1, nxt = cur ^ 1;

        // B-frags: batch-replicated — col lm sources batch lm>>2's h row.
        bf16x8 hb[4];
        #pragma unroll
        for (int kt = 0; kt < 4; ++kt)
            hb[kt] = ldb(&htile[cur][b][kt*32 + lko*8]);

        // 16 MFMA: acc[gt][r] = gate gt of unit w*16+lko*4+r, batch b
        f32x4 acc[4];
        #pragma unroll
        for (int gt = 0; gt < 4; ++gt) acc[gt] = (f32x4){0.f, 0.f, 0.f, 0.f};
        #pragma unroll
        for (int kt = 0; kt < 4; ++kt)
            #pragma unroll
            for (int gt = 0; gt < 4; ++gt)
                acc[gt] = mm16(wf[gt][kt], hb[kt], acc[gt]);

        // in-register select of this lane's 4 gates (reg s of each acc[gt])
        float g4[4];
        #pragma unroll
        for (int gt = 0; gt < 4; ++gt) {
            float a01 = (s & 1) ? acc[gt][1] : acc[gt][0];
            float a23 = (s & 1) ? acc[gt][3] : acc[gt][2];
            g4[gt]    = (s & 2) ? a23 : a01;
        }

        const float keep = dn_c ? 0.0f : 1.0f;
        float gi = fmaf(g4[0], keep, (float)xq_c[0]);
        float gf = fmaf(g4[1], keep, (float)xq_c[1]);
        float gg = fmaf(g4[2], keep, (float)xq_c[2]);
        float go = fmaf(g4[3], keep, (float)xq_c[3]);
        float cp = c_reg * keep;
        float cn = sigmoidf_(gf) * cp + sigmoidf_(gi) * tanhf_(gg);
        float hn = sigmoidf_(go) * tanhf_(cn);
        c_reg = cn;
        h_reg = hn;
        __hip_bfloat16 hnb = f2b(hn);
        htile[nxt][b][un] = hnb;
        // store h_t (bf16 bits as u16) into the consumed xg row — NT stream
        __builtin_nontemporal_store(*(unsigned short*)&hnb, hs_p);

        __syncthreads();

        dn_c = dn_n;
        xq_c = xq_n;
        xq_p += XSTRIDE;
        hs_p += XSTRIDE;
        dn_p += BB;
    }

    // ---- final states (each lane owns one (b,un) pair) ----
    out[3*(size_t)NN + (size_t)(b0 + b)*HH + un] = h_reg;
    out[3*(size_t)NN + (size_t)BB*HH + (size_t)(b0 + b)*HH + un] = c_reg;
}

// ---------------------------------------------------------------------------
// Kernel 3: fused heads — r18 form exactly (4 row-tiles/block, grid 512;
// the r20 grid-256 variant halved CU parallelism and regressed).
// ---------------------------------------------------------------------------
__global__ __launch_bounds__(512) void heads_kernel(
    const __hip_bfloat16* __restrict__ hbuf, // xg base; row n -> hbuf+n*512, 128 bf16
    const int* __restrict__ mask,            // [N,32] bool as int32
    const int* __restrict__ action,          // [N]
    const float* __restrict__ Wa,            // [128,32]
    const float* __restrict__ ba,
    const float* __restrict__ Wc,            // [128]
    const float* __restrict__ bc,
    float* __restrict__ out)
{
    __shared__ __align__(16) __hip_bfloat16 WaT[32][136]; // transposed Wa
    __shared__ __align__(16) __hip_bfloat16 WcB[128];

    const int tid  = threadIdx.x;
    const int lane = tid & 63;
    const int w    = tid >> 6;
    const int lm   = lane & 15;
    const int lko  = lane >> 4;

    // stage WaT[j][k] = Wa[k][j], WcB (once per block)
    for (int idx = tid; idx < 128*32; idx += 512) {
        int k = idx >> 5, j = idx & 31;
        WaT[j][k] = f2b(Wa[idx]);
    }
    if (tid < 128) WcB[tid] = f2b(Wc[tid]);
    __syncthreads();

    // B-frags from LDS: Wa cols lm and 16+lm; Wc in col 0
    bf16x8 wa0[4], wa1[4], wcf[4];
    #pragma unroll
    for (int kt = 0; kt < 4; ++kt) {
        wa0[kt] = ldb(&WaT[lm][kt*32 + lko*8]);
        wa1[kt] = ldb(&WaT[16 + lm][kt*32 + lko*8]);
        bf16x8 z = {};
        wcf[kt] = (lm == 0) ? ldb(&WcB[kt*32 + lko*8]) : z;
    }
    const float ba0 = ba[lm], ba1 = ba[16 + lm], bcv = bc[0];

    #pragma unroll 1
    for (int rt = 0; rt < 4; ++rt) {
        const size_t nbase = (size_t)blockIdx.x * 512 + rt * 128 + w * 16;

        // A-frags: 16 h-rows
        bf16x8 a[4];
        #pragma unroll
        for (int kt = 0; kt < 4; ++kt)
            a[kt] = ldb(hbuf + (nbase + lm)*512 + kt*32 + lko*8);

        f32x4 t0 = {0.f,0.f,0.f,0.f}, t1 = {0.f,0.f,0.f,0.f}, tv = {0.f,0.f,0.f,0.f};
        #pragma unroll
        for (int kt = 0; kt < 4; ++kt) {
            t0 = mm16(a[kt], wa0[kt], t0);
            t1 = mm16(a[kt], wa1[kt], t1);
            tv = mm16(a[kt], wcf[kt], tv);
        }

        #pragma unroll
        for (int r = 0; r < 4; ++r) {
            const size_t n = nbase + lko*4 + r;
            float lg0 = t0[r] + ba0;
            float lg1 = t1[r] + ba1;
            if (mask[n*32 + lm] == 0)      lg0 = -1e8f;
            if (mask[n*32 + 16 + lm] == 0) lg1 = -1e8f;

            float mx = fmaxf(lg0, lg1);
            #pragma unroll
            for (int off = 8; off > 0; off >>= 1)
                mx = fmaxf(mx, __shfl_xor(mx, off, 16));
            float e0 = __expf(lg0 - mx), e1 = __expf(lg1 - mx);
            float s = e0 + e1;
            #pragma unroll
            for (int off = 8; off > 0; off >>= 1)
                s += __shfl_xor(s, off, 16);
            float lse = __logf(s);
            float lp0 = lg0 - mx - lse;
            float lp1 = lg1 - mx - lse;
            float entl = -(e0 * lp0 + e1 * lp1) / s;
            #pragma unroll
            for (int off = 8; off > 0; off >>= 1)
                entl += __shfl_xor(entl, off, 16);

            int act = action[n];
            if (lm == act)      out[n] = lp0;
            if (16 + lm == act) out[n] = lp1;
            if (lm == 0) {
                out[(size_t)NN + n] = entl;
                out[2*(size_t)NN + n] = tv[r] + bcv;
            }
        }
    }
}

extern "C" void kernel_launch(void* const* d_in, const int* in_sizes, int n_in,
                              void* d_out, int out_size, void* d_ws, size_t ws_size,
                              hipStream_t stream) {
    const float* x      = (const float*)d_in[0];
    const int*   done   = (const int*)d_in[1];
    const int*   action = (const int*)d_in[2];
    const int*   mask   = (const int*)d_in[3];
    const float* h0     = (const float*)d_in[4];
    const float* c0     = (const float*)d_in[5];
    const float* W1     = (const float*)d_in[6];
    const float* b1     = (const float*)d_in[7];
    const float* W2     = (const float*)d_in[8];
    const float* b2     = (const float*)d_in[9];
    const float* w_ih   = (const float*)d_in[10];
    const float* w_hh   = (const float*)d_in[11];
    const float* b_ih   = (const float*)d_in[12];
    const float* b_hh   = (const float*)d_in[13];
    const float* Wa     = (const float*)d_in[14];
    const float* ba     = (const float*)d_in[15];
    const float* Wc     = (const float*)d_in[16];
    const float* bc     = (const float*)d_in[17];

    __hip_bfloat16* xg = (__hip_bfloat16*)d_ws;  // [N,512] bf16 = 256 MiB

    // weight scratch in d_out (first 182KB; later overwritten by heads' lp)
    char* wb = (char*)d_out;
    __hip_bfloat16* wih16 = (__hip_bfloat16*)(wb);
    __hip_bfloat16* w1t16 = (__hip_bfloat16*)(wb + 131072);
    __hip_bfloat16* w2t16 = (__hip_bfloat16*)(wb + 147456);
    float*          sbihq = (float*)(wb + 180224);

    prep_kernel<<<32, 512, 0, stream>>>(w_ih, W1, W2, b_ih, b_hh,
                                        wih16, w1t16, w2t16, sbihq);
    trunk_kernel<<<NN/256, 512, 0, stream>>>(x, b1, b2, wih16, w1t16, w2t16,
                                             sbihq, xg);
    lstm_kernel<<<BB/4, 512, 0, stream>>>(xg, xg, w_hh, done, h0, c0, (float*)d_out);
    heads_kernel<<<NN/512, 512, 0, stream>>>(xg, mask, action, Wa, ba, Wc, bc,
                                             (float*)d_out);
}